// Round 3
// baseline (602.797 us; speedup 1.0000x reference)
//
#include <hip/hip_runtime.h>

#define BB 1024
#define FF 64
#define SS 512
#define HH 128
#define ZP 328          // z row pitch in bf16 elems (320 data + 8 pad; mult of 8 -> 16B-aligned b128)
#define ZROWS 16

typedef __attribute__((ext_vector_type(8))) short bf16x8;
typedef __attribute__((ext_vector_type(4))) float f32x4;

__device__ __forceinline__ unsigned short f2bf(float f) {
    unsigned int u = __float_as_uint(f);
    u += 0x7fff + ((u >> 16) & 1);          // RNE
    return (unsigned short)(u >> 16);
}

// ---------------------------------------------------------------------------
// Fold kernel: W_auto-part = W_fold[n][k] = sum_f W_ih[n][f]*W_den[f][k],
// b_fold[n] = sum_f W_ih[n][f]*b_den[f].  ws[0..65535]=W_fold, ws[65536..]=b_fold.
// ---------------------------------------------------------------------------
__global__ void fold_kernel(const float* __restrict__ W_ih,
                            const float* __restrict__ W_den,
                            const float* __restrict__ b_den,
                            float* __restrict__ ws)
{
    const int n = blockIdx.x;      // 512
    const int k = threadIdx.x;     // 128
    float s = 0.f;
    #pragma unroll 8
    for (int f = 0; f < FF; ++f) s = fmaf(W_ih[n*FF + f], W_den[f*HH + k], s);
    ws[n*HH + k] = s;
    if (k == 0) {
        float bsum = 0.f;
        #pragma unroll 8
        for (int f = 0; f < FF; ++f) bsum = fmaf(W_ih[n*FF + f], b_den[f], bsum);
        ws[4*HH*HH + n] = bsum;    // 65536 + n
    }
}

// ---------------------------------------------------------------------------
// Main recurrence. 256 blocks x 512 threads (8 waves). Block owns 4 batch
// rows at M-rows {0,4,8,12} (real rows land in acc reg 0). One barrier/step.
// z = [x_gated | h_teacher | h_auto]; B = [W_ih | W_hh | W_auto] (10 ktiles).
// pred_{t-1} is computed at step t from the same h fragments (deferred pred);
// autoregressive feedback is algebraically folded into W_auto -> never needed.
// ---------------------------------------------------------------------------
__global__ __launch_bounds__(512, 2)
void lstm_mfma_kernel(const float* __restrict__ x,
                      const int* __restrict__ available_len,
                      const int* __restrict__ predict_len,
                      const float* __restrict__ W_ih,
                      const float* __restrict__ W_hh,
                      const float* __restrict__ b_ih,
                      const float* __restrict__ b_hh,
                      const float* __restrict__ W_den,
                      const float* __restrict__ b_den,
                      const float* __restrict__ init_ch,
                      const float* __restrict__ ws,      // fold results (fp32)
                      float* __restrict__ out)
{
    const int b0  = blockIdx.x * 4;
    const int tid = threadIdx.x;
    const int w   = tid >> 6;          // wave 0..7
    const int l   = tid & 63;
    const int l16 = l & 15;
    const int lq  = l >> 4;            // 0..3
    const bool w4 = (w < 4);

    __shared__ __align__(16) unsigned short zbuf[2][ZROWS * ZP];

    for (int i = tid; i < 2 * ZROWS * ZP / 2; i += 512)
        ((unsigned int*)zbuf)[i] = 0u;

    const int a0v = available_len[b0], a1v = available_len[b0+1],
              a2v = available_len[b0+2], a3v = available_len[b0+3];
    const int p0 = predict_len[b0], p1 = predict_len[b0+1],
              p2 = predict_len[b0+2], p3 = predict_len[b0+3];
    const int maxP  = max(max(p0, p1), max(p2, p3));
    const int minAV = min(min(a0v, a1v), min(a2v, a3v));
    const int maxAV = max(max(a0v, a1v), max(a2v, a3v));
    const int P_my  = predict_len[b0 + lq];
    const int AV_my = available_len[b0 + lq];

    // ---- weight fragments: wg[gate][ktile 0..9], bf16, register-resident ----
    bf16x8 wg[4][10];
    float bias_t[4], bias_a[4];
    const float* wfold = ws;
    const float* bfold = ws + 4*HH*HH;
    #pragma unroll
    for (int g = 0; g < 4; ++g) {
        const int n = 128*g + 16*w + l16;
        const float* rih = W_ih  + n * FF;
        const float* rhh = W_hh  + n * HH;
        const float* rfo = wfold + n * HH;
        #pragma unroll
        for (int kt = 0; kt < 2; ++kt) {          // W_ih ktiles
            const int k = 32*kt + 8*lq;
            bf16x8 r;
            #pragma unroll
            for (int i = 0; i < 8; i++) r[i] = (short)f2bf(rih[k + i]);
            wg[g][kt] = r;
        }
        #pragma unroll
        for (int kt = 0; kt < 4; ++kt) {          // W_hh ktiles
            const int k = 32*kt + 8*lq;
            bf16x8 r;
            #pragma unroll
            for (int i = 0; i < 8; i++) r[i] = (short)f2bf(rhh[k + i]);
            wg[g][2 + kt] = r;
        }
        #pragma unroll
        for (int kt = 0; kt < 4; ++kt) {          // W_auto = W_hh + W_fold ktiles
            const int k = 32*kt + 8*lq;
            bf16x8 r;
            #pragma unroll
            for (int i = 0; i < 8; i++) r[i] = (short)f2bf(rhh[k + i] + rfo[k + i]);
            wg[g][6 + kt] = r;
        }
        bias_t[g] = b_ih[n] + b_hh[n];
        bias_a[g] = bias_t[g] + bfold[n];
    }

    // pred weights (waves 0-3): f = 16w + l16
    bf16x8 wd[4];
    float bden = 0.f;
    size_t xbase = 0;
    int AV_x = 0;
    if (w4) {
        const int f = 16*w + l16;
        const float* rd = W_den + f * HH;
        #pragma unroll
        for (int kt = 0; kt < 4; ++kt) {
            const int k = 32*kt + 8*lq;
            bf16x8 r;
            #pragma unroll
            for (int i = 0; i < 8; i++) r[i] = (short)f2bf(rd[k + i]);
            wd[kt] = r;
        }
        bden = b_den[f];
        xbase = ((size_t)(b0 + w) * FF + l) * SS;
        AV_x  = available_len[b0 + w];
    }

    const int unit = 16*w + l16;
    float c = init_ch[unit];
    const float h0v = init_ch[HH + unit];

    __syncthreads();                    // zeroing complete

    // init buf0: h0 -> teacher slot (t=0 < AV always), x0 -> x slot
    zbuf[0][(4*lq)*ZP + 64 + unit] = f2bf(h0v);
    if (w4) zbuf[0][(4*w)*ZP + l] = f2bf(x[xbase]);

    int cur = 0;
    for (int t = 0; t <= maxP; ++t) {
        __syncthreads();                               // B1 (only barrier)
        const unsigned short* zc = zbuf[cur];
        const bool anyT = (t < maxAV);
        const bool anyA = (t >= minAV);
        const bool last = (t == maxP);
        const bool dop  = w4 && (t > 0);
        const int abase = l16*ZP + 8*lq;

        // x prefetch (latency hidden under MFMAs)
        float xv = 0.f;
        const bool xl = w4 && !last && (t + 1 < AV_x);
        if (xl) xv = x[xbase + t + 1];

        f32x4 pa  = {0.f,0.f,0.f,0.f};
        f32x4 ac0 = {0.f,0.f,0.f,0.f}, ac1 = {0.f,0.f,0.f,0.f},
              ac2 = {0.f,0.f,0.f,0.f}, ac3 = {0.f,0.f,0.f,0.f};

        if (anyT) {
            if (!last) {
                bf16x8 a0 = *(const bf16x8*)(zc + abase + 0);
                bf16x8 a1 = *(const bf16x8*)(zc + abase + 32);
                ac0 = __builtin_amdgcn_mfma_f32_16x16x32_bf16(a0, wg[0][0], ac0, 0,0,0);
                ac1 = __builtin_amdgcn_mfma_f32_16x16x32_bf16(a0, wg[1][0], ac1, 0,0,0);
                ac2 = __builtin_amdgcn_mfma_f32_16x16x32_bf16(a0, wg[2][0], ac2, 0,0,0);
                ac3 = __builtin_amdgcn_mfma_f32_16x16x32_bf16(a0, wg[3][0], ac3, 0,0,0);
                ac0 = __builtin_amdgcn_mfma_f32_16x16x32_bf16(a1, wg[0][1], ac0, 0,0,0);
                ac1 = __builtin_amdgcn_mfma_f32_16x16x32_bf16(a1, wg[1][1], ac1, 0,0,0);
                ac2 = __builtin_amdgcn_mfma_f32_16x16x32_bf16(a1, wg[2][1], ac2, 0,0,0);
                ac3 = __builtin_amdgcn_mfma_f32_16x16x32_bf16(a1, wg[3][1], ac3, 0,0,0);
            }
            #pragma unroll
            for (int kt = 0; kt < 4; ++kt) {           // teacher-h slot
                bf16x8 v = *(const bf16x8*)(zc + abase + 64 + 32*kt);
                if (dop) pa = __builtin_amdgcn_mfma_f32_16x16x32_bf16(v, wd[kt], pa, 0,0,0);
                if (!last) {
                    ac0 = __builtin_amdgcn_mfma_f32_16x16x32_bf16(v, wg[0][2+kt], ac0, 0,0,0);
                    ac1 = __builtin_amdgcn_mfma_f32_16x16x32_bf16(v, wg[1][2+kt], ac1, 0,0,0);
                    ac2 = __builtin_amdgcn_mfma_f32_16x16x32_bf16(v, wg[2][2+kt], ac2, 0,0,0);
                    ac3 = __builtin_amdgcn_mfma_f32_16x16x32_bf16(v, wg[3][2+kt], ac3, 0,0,0);
                }
            }
        }
        if (anyA) {
            #pragma unroll
            for (int kt = 0; kt < 4; ++kt) {           // auto-h slot
                bf16x8 v = *(const bf16x8*)(zc + abase + 192 + 32*kt);
                if (dop) pa = __builtin_amdgcn_mfma_f32_16x16x32_bf16(v, wd[kt], pa, 0,0,0);
                if (!last) {
                    ac0 = __builtin_amdgcn_mfma_f32_16x16x32_bf16(v, wg[0][6+kt], ac0, 0,0,0);
                    ac1 = __builtin_amdgcn_mfma_f32_16x16x32_bf16(v, wg[1][6+kt], ac1, 0,0,0);
                    ac2 = __builtin_amdgcn_mfma_f32_16x16x32_bf16(v, wg[2][6+kt], ac2, 0,0,0);
                    ac3 = __builtin_amdgcn_mfma_f32_16x16x32_bf16(v, wg[3][6+kt], ac3, 0,0,0);
                }
            }
        }

        // deferred pred store: out[t-1][b0+lq][16w+l16]
        if (dop && (t - 1 < P_my)) {
            out[(size_t)(t-1) * BB * FF + (size_t)(b0 + lq) * FF + 16*w + l16] = pa[0] + bden;
        }

        if (!last) {
            const bool auto_my = (t >= AV_my);
            const float g0 = ac0[0] + (auto_my ? bias_a[0] : bias_t[0]);
            const float g1 = ac1[0] + (auto_my ? bias_a[1] : bias_t[1]);
            const float g2 = ac2[0] + (auto_my ? bias_a[2] : bias_t[2]);
            const float g3 = ac3[0] + (auto_my ? bias_a[3] : bias_t[3]);

            const float si = 1.f / (1.f + __expf(-g0));
            const float sf = 1.f / (1.f + __expf(-g1));
            const float tg = 1.f - 2.f / (__expf(2.f * g2) + 1.f);
            const float so = 1.f / (1.f + __expf(-g3));
            const float cn = sf * c + si * tg;
            const float tc = 1.f - 2.f / (__expf(2.f * cn) + 1.f);
            const float hn = so * tc;

            const bool sel = (t < P_my);
            if (sel) c = cn;

            const int nxt = cur ^ 1;
            const unsigned short hbf = f2bf(hn);
            const bool teach_next = (t + 1 < AV_my);
            if (sel) {
                zbuf[nxt][(4*lq)*ZP +  64 + unit] = teach_next ? hbf : (unsigned short)0;
                zbuf[nxt][(4*lq)*ZP + 192 + unit] = teach_next ? (unsigned short)0 : hbf;
            }
            if (w4) zbuf[nxt][(4*w)*ZP + l] = xl ? f2bf(xv) : (unsigned short)0;
            cur = nxt;
        }
    }
}

// ---------------------------------------------------------------------------
// Tail: for t >= predict_len[b], out[t][b][f] = x[b][f][t].
// ---------------------------------------------------------------------------
__global__ void tail_copy(const float* __restrict__ x,
                          const int* __restrict__ predict_len,
                          float* __restrict__ out)
{
    __shared__ float tile[64][65];
    const int b  = blockIdx.x;
    const int t0 = blockIdx.y * 64;
    const int P  = predict_len[b];
    if (t0 + 64 <= P) return;

    const int tid = threadIdx.x;         // 256
    const int tt  = tid & 63;
    const int fb  = tid >> 6;
    #pragma unroll
    for (int i = 0; i < 16; i++) {
        int f = fb * 16 + i;
        tile[f][tt] = x[(size_t)b * FF * SS + (size_t)f * SS + t0 + tt];
    }
    __syncthreads();
    const int f2 = tid & 63;
    const int tb = tid >> 6;
    #pragma unroll
    for (int i = 0; i < 16; i++) {
        int tloc = tb * 16 + i;
        int t    = t0 + tloc;
        if (t >= P) out[(size_t)t * BB * FF + (size_t)b * FF + f2] = tile[f2][tloc];
    }
}

extern "C" void kernel_launch(void* const* d_in, const int* in_sizes, int n_in,
                              void* d_out, int out_size, void* d_ws, size_t ws_size,
                              hipStream_t stream) {
    const float* x       = (const float*)d_in[0];
    const int*   avail   = (const int*)  d_in[1];
    const int*   plen    = (const int*)  d_in[2];
    const float* W_ih    = (const float*)d_in[3];
    const float* W_hh    = (const float*)d_in[4];
    const float* b_ih    = (const float*)d_in[5];
    const float* b_hh    = (const float*)d_in[6];
    const float* W_den   = (const float*)d_in[7];
    const float* b_den   = (const float*)d_in[8];
    const float* init_ch = (const float*)d_in[9];
    float*       out     = (float*)d_out;
    float*       ws      = (float*)d_ws;       // needs 264 KB

    fold_kernel<<<dim3(4*HH), dim3(HH), 0, stream>>>(W_ih, W_den, b_den, ws);
    tail_copy<<<dim3(BB, SS/64), dim3(256), 0, stream>>>(x, plen, out);
    lstm_mfma_kernel<<<dim3(BB/4), dim3(512), 0, stream>>>(
        x, avail, plen, W_ih, W_hh, b_ih, b_hh, W_den, b_den, init_ch, ws, out);
}